// Round 3
// 396.817 us; speedup vs baseline: 1.0367x; 1.0367x over previous
//
#include <hip/hip_runtime.h>
#include <math.h>

#define Bn 64
#define Cn 64
#define Nn 325
#define Tn 12
#define NT (Nn * Tn)           // 3900
#define ROWS (Bn * Tn * Nn)    // 249600 rows of the output softmax
#define QUADS (ROWS / 4)       // 62400 pool quads (4 rows each)
#define POOL_BLOCKS ((QUADS + 255) / 256)        // 244
#define DIST_BLOCKS ((Nn * Nn + 255) / 256)      // 413

#define RPB 16                         // rows per softmax block (16*1300B = 20800B, 16B-aligned region)
#define SMX_BLOCKS (ROWS / RPB)        // 15600 (exact)
#define STAGE4 (RPB * Nn / 4)          // 1300 float4 per block

typedef float f32x4 __attribute__((ext_vector_type(4)));   // nontemporal-store-compatible

// softplus matching jax.nn.softplus = max(x,0) + log1p(exp(-|x|))
__device__ __forceinline__ float sp(float x) {
    return fmaxf(x, 0.0f) + log1pf(expf(-fabsf(x)));
}

// Fused prep: blocks [0, POOL_BLOCKS) do pooled-mean -> softplus+1 -> pow;
// blocks [POOL_BLOCKS, +DIST_BLOCKS) do dist2 = dist^(2*l3).
// Pool mapping: quad q covers tids [4q, 4q+4), tid = b*NT + n*Tn + t (t fastest).
// NT % 4 == 0 and Tn % 4 == 0 so a quad never crosses b; float4 loads are
// 16B-aligned (b*Cn*NT, c*NT, r0 all multiples of 4 floats).
__global__ __launch_bounds__(256)
void prep_kernel(const float* __restrict__ x, const float* __restrict__ dist,
                 const float* __restrict__ l1p, const float* __restrict__ l2p,
                 const float* __restrict__ l3p,
                 float* __restrict__ x1p, float* __restrict__ x2p,
                 float* __restrict__ dist2) {
    int bid = blockIdx.x;
    if (bid < POOL_BLOCKS) {
        int q = bid * 256 + threadIdx.x;
        if (q >= QUADS) return;
        int tid0 = q * 4;
        int b = tid0 / NT;
        int r0 = tid0 - b * NT;
        const float4* p = (const float4*)(x + (size_t)b * Cn * NT + r0);
        const int cstride = NT / 4;   // 975 float4s between channels

        float4 s1 = make_float4(0.f, 0.f, 0.f, 0.f);
        float4 s2 = make_float4(0.f, 0.f, 0.f, 0.f);
#pragma unroll
        for (int c = 0; c < 32; ++c) {
            float4 v = p[c * cstride];
            s1.x += v.x; s1.y += v.y; s1.z += v.z; s1.w += v.w;
        }
#pragma unroll
        for (int c = 32; c < 64; ++c) {
            float4 v = p[c * cstride];
            s2.x += v.x; s2.y += v.y; s2.z += v.z; s2.w += v.w;
        }

        float l1 = sp(l1p[0]);
        float l2 = sp(l2p[0]);
        float a1[4] = {s1.x, s1.y, s1.z, s1.w};
        float a2[4] = {s2.x, s2.y, s2.z, s2.w};
#pragma unroll
        for (int m = 0; m < 4; ++m) {
            int r = r0 + m;
            int n = r / Tn;
            int t = r - n * Tn;
            int o = (b * Tn + t) * Nn + n;   // [bt, n] layout
            float v1 = sp(a1[m] * (1.0f / 32.0f)) + 1.0f;
            float v2 = sp(a2[m] * (1.0f / 32.0f)) + 1.0f;
            x1p[o] = powf(v1, l1);
            x2p[o] = powf(v2, l2);
        }
    } else {
        int tid = (bid - POOL_BLOCKS) * 256 + threadIdx.x;
        if (tid >= Nn * Nn) return;
        float e = 2.0f * sp(l3p[0]);
        dist2[tid] = powf(dist[tid], e);
    }
}

// Softmax v2: one block = 16 consecutive output rows (4 waves x 4 rows each).
//  - x2row(s) for the block's <=2 distinct bt values staged in LDS once
//    (16x fewer x2p global reads than per-row loading).
//  - Row results staged in LDS, then the block's contiguous 20800B output
//    region is streamed with 16B-aligned nontemporal float4 stores
//    (20800 * blockIdx is 16B-aligned; scalar 4B stores at wid*1300 were not).
//  - a_ij = s1 * p_j with s1 = g*x1_i > 0 and p_j = x2_j * d_ij, so
//    exp(a - amax) = exp((p - pmax)*s1): max/exp pass needs 1 mul + fmax per elem.
__global__ __launch_bounds__(256)
void softmax_kernel(const float* __restrict__ x1p,
                    const float* __restrict__ x2p,
                    const float* __restrict__ dist2,
                    const float* __restrict__ Gp,
                    float* __restrict__ out) {
    __shared__ __align__(16) float stage[RPB * Nn];   // 20800 B
    __shared__ float x2s[2][Nn];                      // 2600 B

    const int tid  = threadIdx.x;
    const int wave = tid >> 6;
    const int lane = tid & 63;
    const int wid0 = blockIdx.x * RPB;

    const int bt0 = wid0 / Nn;
    const int btL = (wid0 + RPB - 1) / Nn;   // last row's bt (== bt0 or bt0+1)

    for (int j = tid; j < Nn; j += 256) x2s[0][j] = x2p[bt0 * Nn + j];
    if (btL != bt0) {
        for (int j = tid; j < Nn; j += 256) x2s[1][j] = x2p[btL * Nn + j];
    }
    __syncthreads();

    const float g = sp(Gp[0]);

    for (int r = wave * 4; r < wave * 4 + 4; ++r) {
        const int wid = wid0 + r;
        const int bt  = wid / Nn;
        const int i   = wid - bt * Nn;
        const float* x2row = x2s[bt != bt0 ? 1 : 0];
        const float* drow  = dist2 + i * Nn;
        const float s1 = g * x1p[wid];      // > 0 always (softplus-derived)

        float p[6];
        float m = -INFINITY;
#pragma unroll
        for (int k = 0; k < 6; ++k) {
            int j = lane + 64 * k;
            float pv = -INFINITY;
            if (j < Nn) pv = x2row[j] * drow[j];
            p[k] = pv;
            m = fmaxf(m, pv);
        }
#pragma unroll
        for (int off = 32; off; off >>= 1) m = fmaxf(m, __shfl_xor(m, off, 64));

        float s = 0.0f;
#pragma unroll
        for (int k = 0; k < 6; ++k) {
            int j = lane + 64 * k;
            float e = 0.0f;
            if (j < Nn) e = expf((p[k] - m) * s1);
            p[k] = e;
            s += e;
        }
#pragma unroll
        for (int off = 32; off; off >>= 1) s += __shfl_xor(s, off, 64);

        const float inv = 1.0f / s;
        float* srow = stage + r * Nn;
#pragma unroll
        for (int k = 0; k < 6; ++k) {
            int j = lane + 64 * k;
            if (j < Nn) srow[j] = p[k] * inv;
        }
    }
    __syncthreads();

    // Streaming store of the block's whole region: 1300 float4, 16B-aligned.
    const f32x4* src = (const f32x4*)stage;
    f32x4* dst = (f32x4*)(out + (size_t)wid0 * Nn);
#pragma unroll
    for (int it = 0; it < (STAGE4 + 255) / 256; ++it) {
        int idx = it * 256 + tid;
        if (idx < STAGE4) __builtin_nontemporal_store(src[idx], dst + idx);
    }
}

extern "C" void kernel_launch(void* const* d_in, const int* in_sizes, int n_in,
                              void* d_out, int out_size, void* d_ws, size_t ws_size,
                              hipStream_t stream) {
    const float* x    = (const float*)d_in[0];
    const float* dist = (const float*)d_in[1];
    const float* l1   = (const float*)d_in[2];
    const float* l2   = (const float*)d_in[3];
    const float* l3   = (const float*)d_in[4];
    const float* G    = (const float*)d_in[5];
    float* out = (float*)d_out;

    float* ws    = (float*)d_ws;
    float* x1p   = ws;                 // ROWS floats
    float* x2p   = ws + ROWS;          // ROWS floats
    float* dist2 = ws + 2 * ROWS;      // Nn*Nn floats (total ~2.4 MB)

    prep_kernel<<<POOL_BLOCKS + DIST_BLOCKS, 256, 0, stream>>>(
        x, dist, l1, l2, l3, x1p, x2p, dist2);
    softmax_kernel<<<SMX_BLOCKS, 256, 0, stream>>>(x1p, x2p, dist2, G, out);
}

// Round 4
// 396.589 us; speedup vs baseline: 1.0373x; 1.0006x over previous
//
#include <hip/hip_runtime.h>
#include <math.h>

#define Bn 64
#define Cn 64
#define Nn 325
#define Tn 12
#define NT (Nn * Tn)           // 3900
#define ROWS (Bn * Tn * Nn)    // 249600 rows of the output softmax
#define QUADS (ROWS / 4)       // 62400 pool quads (4 rows each)
#define POOL_BLOCKS ((QUADS + 255) / 256)        // 244
#define DIST_BLOCKS ((Nn * Nn + 255) / 256)      // 413

#define RPB 16                               // rows per softmax block (4 waves x 4 rows)
#define CHUNKS ((Nn + RPB - 1) / RPB)        // 21 row-chunks per bt (last has 5 rows)
#define SMX_BLOCKS (Bn * Tn * CHUNKS)        // 16128 blocks, each bt-pure
#define LOG2E 1.4426950408889634f

// softplus matching jax.nn.softplus = max(x,0) + log1p(exp(-|x|))
__device__ __forceinline__ float sp(float x) {
    return fmaxf(x, 0.0f) + log1pf(expf(-fabsf(x)));
}

// Fused prep: blocks [0, POOL_BLOCKS) do pooled-mean -> softplus+1 -> pow;
// blocks [POOL_BLOCKS, +DIST_BLOCKS) do dist2 = dist^(2*l3).
__global__ __launch_bounds__(256)
void prep_kernel(const float* __restrict__ x, const float* __restrict__ dist,
                 const float* __restrict__ l1p, const float* __restrict__ l2p,
                 const float* __restrict__ l3p,
                 float* __restrict__ x1p, float* __restrict__ x2p,
                 float* __restrict__ dist2) {
    int bid = blockIdx.x;
    if (bid < POOL_BLOCKS) {
        int q = bid * 256 + threadIdx.x;
        if (q >= QUADS) return;
        int tid0 = q * 4;
        int b = tid0 / NT;
        int r0 = tid0 - b * NT;
        const float4* p = (const float4*)(x + (size_t)b * Cn * NT + r0);
        const int cstride = NT / 4;   // 975 float4s between channels

        float4 s1 = make_float4(0.f, 0.f, 0.f, 0.f);
        float4 s2 = make_float4(0.f, 0.f, 0.f, 0.f);
#pragma unroll
        for (int c = 0; c < 32; ++c) {
            float4 v = p[c * cstride];
            s1.x += v.x; s1.y += v.y; s1.z += v.z; s1.w += v.w;
        }
#pragma unroll
        for (int c = 32; c < 64; ++c) {
            float4 v = p[c * cstride];
            s2.x += v.x; s2.y += v.y; s2.z += v.z; s2.w += v.w;
        }

        float l1 = sp(l1p[0]);
        float l2 = sp(l2p[0]);
        float a1[4] = {s1.x, s1.y, s1.z, s1.w};
        float a2[4] = {s2.x, s2.y, s2.z, s2.w};
#pragma unroll
        for (int m = 0; m < 4; ++m) {
            int r = r0 + m;
            int n = r / Tn;
            int t = r - n * Tn;
            int o = (b * Tn + t) * Nn + n;   // [bt, n] layout
            float v1 = sp(a1[m] * (1.0f / 32.0f)) + 1.0f;
            float v2 = sp(a2[m] * (1.0f / 32.0f)) + 1.0f;
            x1p[o] = powf(v1, l1);
            x2p[o] = powf(v2, l2);
        }
    } else {
        int tid = (bid - POOL_BLOCKS) * 256 + threadIdx.x;
        if (tid >= Nn * Nn) return;
        float e = 2.0f * sp(l3p[0]);
        dist2[tid] = powf(dist[tid], e);
    }
}

// Softmax v3 — instruction-minimized, no LDS.
//  Round-3 post-mortem: kernel is issue-bound, not memory-bound (dist2/x2p are
//  L2-resident; writes = 324.5 MB = 51 us at roofline but kernel ran ~180 us).
//  - bt-pure blocks: block = (bt, chunk of <=16 rows). x2row loaded ONCE per
//    wave into 6 registers, reused across its 4 rows (kills all x2 LDS traffic).
//  - exp((p-m)*s1) = exp2(fma(p, s1e, -m*s1e)), s1e = g*x1*log2(e):
//    3 VALU/elem in the exp pass instead of 5.
//  - 4 rows per wave processed fully unrolled & interleaved: the four 6-step
//    shuffle-reduce chains pipeline; 24 dist2 loads issue early. Static indices
//    only (runtime-indexed arrays would spill to scratch).
//  - Direct nontemporal scalar stores: 256 B contiguous per wave-instruction;
//    L2 merges line straddles, HBM sees full lines. No stage, no barrier.
//  - Tail chunk (5 rows): clamp row index for loads (no OOB), guard stores.
__global__ __launch_bounds__(256)
void softmax_kernel(const float* __restrict__ x1p,
                    const float* __restrict__ x2p,
                    const float* __restrict__ dist2,
                    const float* __restrict__ Gp,
                    float* __restrict__ out) {
    const int bid   = blockIdx.x;
    const int bt    = bid / CHUNKS;
    const int chunk = bid - bt * CHUNKS;
    const int i0    = chunk * RPB;
    const int wave  = threadIdx.x >> 6;
    const int lane  = threadIdx.x & 63;
    const int iw    = i0 + wave * 4;          // this wave's first row

    const float g = sp(Gp[0]);
    const float* x2row = x2p + bt * Nn;
    const float* x1row = x1p + bt * Nn;

    // x2 fragment in registers, reused for all 4 rows of this wave
    float x2r[6];
#pragma unroll
    for (int k = 0; k < 6; ++k) {
        int j = lane + 64 * k;
        x2r[k] = (j < Nn) ? x2row[j] : 0.0f;   // only k=5 actually masks
    }

    float p[4][6];
    float mx[4], sum[4], s1e[4];

    // Pass 1: p = x2*d, per-row running max (rows interleaved)
#pragma unroll
    for (int r = 0; r < 4; ++r) {
        int ic = min(iw + r, Nn - 1);          // clamp: no OOB read on tail
        const float* drow = dist2 + ic * Nn;
        float m = -INFINITY;
#pragma unroll
        for (int k = 0; k < 6; ++k) {
            int j = lane + 64 * k;
            float pv = -INFINITY;
            if (j < Nn) pv = x2r[k] * drow[j];
            p[r][k] = pv;
            m = fmaxf(m, pv);
        }
        mx[r] = m;
        s1e[r] = g * x1row[ic] * LOG2E;        // > 0 (softplus-derived)
    }
    // interleaved butterfly max-reduce (4 independent chains pipeline)
#pragma unroll
    for (int off = 32; off; off >>= 1) {
#pragma unroll
        for (int r = 0; r < 4; ++r) mx[r] = fmaxf(mx[r], __shfl_xor(mx[r], off, 64));
    }

    // Pass 2: e = 2^(p*s1e - m*s1e), per-row sum
#pragma unroll
    for (int r = 0; r < 4; ++r) {
        float bshift = -mx[r] * s1e[r];
        float s = 0.0f;
#pragma unroll
        for (int k = 0; k < 6; ++k) {
            float e = exp2f(fmaf(p[r][k], s1e[r], bshift));  // -inf lanes -> 0
            p[r][k] = e;
            s += e;
        }
        sum[r] = s;
    }
#pragma unroll
    for (int off = 32; off; off >>= 1) {
#pragma unroll
        for (int r = 0; r < 4; ++r) sum[r] += __shfl_xor(sum[r], off, 64);
    }

    // Pass 3: normalize + direct nontemporal stores (coalesced 256 B/instr)
#pragma unroll
    for (int r = 0; r < 4; ++r) {
        int i = iw + r;
        if (i < Nn) {                          // wave-uniform guard
            float inv = 1.0f / sum[r];
            float* orow = out + ((size_t)bt * Nn + i) * (size_t)Nn;
#pragma unroll
            for (int k = 0; k < 6; ++k) {
                int j = lane + 64 * k;
                if (j < Nn) __builtin_nontemporal_store(p[r][k] * inv, orow + j);
            }
        }
    }
}

extern "C" void kernel_launch(void* const* d_in, const int* in_sizes, int n_in,
                              void* d_out, int out_size, void* d_ws, size_t ws_size,
                              hipStream_t stream) {
    const float* x    = (const float*)d_in[0];
    const float* dist = (const float*)d_in[1];
    const float* l1   = (const float*)d_in[2];
    const float* l2   = (const float*)d_in[3];
    const float* l3   = (const float*)d_in[4];
    const float* G    = (const float*)d_in[5];
    float* out = (float*)d_out;

    float* ws    = (float*)d_ws;
    float* x1p   = ws;                 // ROWS floats
    float* x2p   = ws + ROWS;          // ROWS floats
    float* dist2 = ws + 2 * ROWS;      // Nn*Nn floats (total ~2.4 MB)

    prep_kernel<<<POOL_BLOCKS + DIST_BLOCKS, 256, 0, stream>>>(
        x, dist, l1, l2, l3, x1p, x2p, dist2);
    softmax_kernel<<<SMX_BLOCKS, 256, 0, stream>>>(x1p, x2p, dist2, G, out);
}